// Round 6
// baseline (328.187 us; speedup 1.0000x reference)
//
#include <hip/hip_runtime.h>

typedef __attribute__((ext_vector_type(8))) short bf16x8;
typedef __attribute__((ext_vector_type(4))) float f32x4;
typedef __attribute__((ext_vector_type(4))) unsigned short us4;

#define AS1 __attribute__((address_space(1)))
#define AS3 __attribute__((address_space(3)))

__device__ __forceinline__ unsigned short f2bf(float f) {
  unsigned u = __float_as_uint(f);
  u += 0x7fff + ((u >> 16) & 1);   // RNE
  return (unsigned short)(u >> 16);
}

__device__ __forceinline__ void gload_lds16(const void* g, void* l) {
  __builtin_amdgcn_global_load_lds((const AS1 unsigned int*)g,
                                   (AS3 unsigned int*)l, 16, 0, 0);
}

#define MFMA16(a, b, c) __builtin_amdgcn_mfma_f32_16x16x32_bf16(a, b, c, 0, 0, 0)

// ---------------------------------------------------------------------------
// BM=256 x BN=128, BK=32 bf16 GEMM, one window per K-tile, 3-deep LDS ring,
// 72 KB LDS -> 2 blocks/CU (round-6: round-4 geometry + round-5 conflict-free
// chunk-major layout; both validated independently).
// C[M,N] = scale*(A[M,K] @ Bt[N,K]^T) + bias.
// 512 thr = 8 waves (4M x 2N): wm = wave>>1, wn = wave&1; per-wave 64x64 =
// acc[4][4] of 16x16x32 MFMA.
//
// LDS layout (chunk-major): each 16-row x 32-col fragment block (1 KB)
// stores element (r16, chunk, j) at ushort offset (chunk*16 + r16)*8 + j.
// Fragment read for block b: lane reads &lds[b*512 + lane*8] -> linear in
// lane -> SAME pattern as the global_load_lds write (base + lane*16B) ->
// ZERO bank conflicts both sides (verified round 5: SQ_LDS_BANK_CONFLICT=0).
// Stage call (128 rows x 32 cols, one gload/thread): lane fetches global
// (row = wave*16 + (lane&15), chunk = lane>>4); LDS dest = call_base +
// wave*512 (wave-uniform, linear).  3 calls/tile: A 0-127, A 128-255, B.
//
// Window t: stage(t+2) [3 gloads] ; ds_read af[4], bf[4] of tile t ;
// 16 MFMA ; vmcnt(3) ; s_barrier.
//   Steady state at wait: outstanding = 6 -> vmcnt(3) drains exactly
//   stage(t+1), one full window ahead of its reads.  Per-wave vmcnt +
//   barrier => tile complete CU-wide (all waves issue identical call
//   sequences).  Tail: t+2==NT -> vmcnt(0); last window -> no wait.
// WAR: stage(t+2) overwrites buf[(t-1)%3]; its ds_reads were lgkm-drained
// before window t-1's MFMAs, then the end-of-(t-1) barrier was crossed.
//
// MODE 0: C[bz*sC + row*ldc + col].  MODE 1 (fused QKV): piece = col0>>10
// (wave-uniform); pieces 0,1 -> compact [8192][1024] at C + piece*sC;
// piece 2 -> V transposed to Vt[b][d][2048], b = blockIdx.x>>3.
// ---------------------------------------------------------------------------
template <typename OutT, bool BIAS, int MODE>
__global__ __launch_bounds__(512, 2) void gemmk(
    const unsigned short* __restrict__ A,
    const unsigned short* __restrict__ Bt,
    OutT* __restrict__ C,
    unsigned short* __restrict__ Vt,
    const float* __restrict__ bias,
    int Kd, int lda, int ldb, int ldc,
    long sA, long sB, long sC,
    float scale) {
  constexpr int ABUF  = 256 * 32;            // 8192 ushorts (16 KB)
  constexpr int BUFSZ = ABUF + 128 * 32;     // 12288 ushorts = 24 KB
  __shared__ unsigned short lds[3 * BUFSZ];  // 72 KB -> 2 blocks/CU

  const int bz = blockIdx.z;
  A  += (size_t)bz * sA + (size_t)blockIdx.x * 256 * lda;
  Bt += (size_t)bz * sB + (size_t)blockIdx.y * 128 * ldb;

  const int tid  = threadIdx.x;
  const int wave = tid >> 6;
  const int lane = tid & 63;
  const int wm   = wave >> 1;              // 0..3
  const int wn   = wave & 1;               // 0..1
  const int l15  = lane & 15;
  const int hi   = lane >> 4;              // 0..3
  // stage-side: lane covers global (row = wave*16 + (lane&15), chunk = lane>>4)
  const int srow = wave * 16 + l15;        // 0..127 within a call
  const int scol = hi * 8;                 // ushort col offset

  auto stage = [&](int bi, int k0) {
    unsigned short* L = &lds[bi * BUFSZ + wave * 512];       // wave-uniform
    const unsigned short* ga = A + (size_t)srow * lda + (k0 + scol);
    gload_lds16(ga, L);                                      // A rows 0-127
    gload_lds16(ga + (size_t)128 * lda, L + 4096);           // A rows 128-255
    gload_lds16(Bt + (size_t)srow * ldb + (k0 + scol), L + ABUF);  // B 0-127
  };

  f32x4 acc[4][4] = {};

  // prologue: stage tiles 0,1; drain tile 0 (keep tile 1 in flight)
  stage(0, 0);
  stage(1, 32);
  asm volatile("s_waitcnt vmcnt(3)" ::: "memory");
  __builtin_amdgcn_s_barrier();

  const int NT = Kd >> 5;
  int bufi = 0;
  const int rdoff = lane * 8;              // linear-in-lane (conflict-free)
  for (int t = 0; t < NT; ++t) {
    if (t + 2 < NT) {
      int nbi = bufi + 2; if (nbi >= 3) nbi -= 3;
      stage(nbi, (t + 2) << 5);
    }
    const unsigned short* L = &lds[bufi * BUFSZ];
    bf16x8 af[4], bf[4];
#pragma unroll
    for (int mt = 0; mt < 4; ++mt)
      af[mt] = *(const bf16x8*)&L[(wm * 4 + mt) * 512 + rdoff];
#pragma unroll
    for (int nt = 0; nt < 4; ++nt)
      bf[nt] = *(const bf16x8*)&L[ABUF + (wn * 4 + nt) * 512 + rdoff];
    __builtin_amdgcn_s_setprio(1);
#pragma unroll
    for (int mt = 0; mt < 4; ++mt)
#pragma unroll
      for (int nt = 0; nt < 4; ++nt)
        acc[mt][nt] = MFMA16(af[mt], bf[nt], acc[mt][nt]);
    __builtin_amdgcn_s_setprio(0);
    if (t + 2 < NT)      asm volatile("s_waitcnt vmcnt(3)" ::: "memory");
    else if (t + 1 < NT) asm volatile("s_waitcnt vmcnt(0)" ::: "memory");
    __builtin_amdgcn_s_barrier();
    bufi = (bufi + 1 == 3) ? 0 : bufi + 1;
  }

  // ------------------------------- epilogue -------------------------------
  const int hi4  = hi << 2;
  const int row0 = blockIdx.x * 256 + wm * 64;
  const int col0 = blockIdx.y * 128 + wn * 64;

  if constexpr (MODE == 1) {
    const int piece = col0 >> 10;                 // wave-uniform
    float bvv[4];
#pragma unroll
    for (int nt = 0; nt < 4; ++nt)
      bvv[nt] = BIAS ? bias[col0 + nt * 16 + l15] : 0.0f;
    if (piece < 2) {
      OutT* dst = C + (size_t)piece * sC;
      const int cb = (col0 & 1023) + l15;
#pragma unroll
      for (int mt = 0; mt < 4; ++mt)
#pragma unroll
        for (int r = 0; r < 4; ++r) {
          const size_t rowoff = (size_t)(row0 + mt * 16 + hi4 + r) * ldc;
#pragma unroll
          for (int nt = 0; nt < 4; ++nt)
            dst[rowoff + cb + nt * 16] = (OutT)f2bf(acc[mt][nt][r] * scale + bvv[nt]);
        }
    } else {
      // V piece: write transposed Vt[b][d][2048]
      const int b = blockIdx.x >> 3;
      const int sb = (blockIdx.x & 7) * 256 + wm * 64 + hi4;
#pragma unroll
      for (int nt = 0; nt < 4; ++nt) {
        const int d = ((col0 + nt * 16) & 1023) + l15;
#pragma unroll
        for (int mt = 0; mt < 4; ++mt) {
          us4 pk;
          pk.x = f2bf(acc[mt][nt][0] * scale + bvv[nt]);
          pk.y = f2bf(acc[mt][nt][1] * scale + bvv[nt]);
          pk.z = f2bf(acc[mt][nt][2] * scale + bvv[nt]);
          pk.w = f2bf(acc[mt][nt][3] * scale + bvv[nt]);
          *(us4*)&Vt[((size_t)b << 21) + (size_t)d * 2048 + sb + mt * 16] = pk;
        }
      }
    }
  } else {
    C += (size_t)bz * sC;
    float bvv[4];
#pragma unroll
    for (int nt = 0; nt < 4; ++nt)
      bvv[nt] = BIAS ? bias[col0 + nt * 16 + l15] : 0.0f;
    const int cb = col0 + l15;
#pragma unroll
    for (int mt = 0; mt < 4; ++mt)
#pragma unroll
      for (int r = 0; r < 4; ++r) {
        const size_t rowoff = (size_t)(row0 + mt * 16 + hi4 + r) * ldc;
#pragma unroll
        for (int nt = 0; nt < 4; ++nt) {
          const float v = acc[mt][nt][r] * scale + bvv[nt];
          if constexpr (sizeof(OutT) == 4)
            C[rowoff + cb + nt * 16] = v;
          else
            C[rowoff + cb + nt * 16] = (OutT)f2bf(v);
        }
      }
  }
}

// fp32 -> bf16 flat convert (4 elems/thread)
__global__ void cvt_x(const float* __restrict__ in, unsigned short* __restrict__ out, int n4) {
  const int i = blockIdx.x * blockDim.x + threadIdx.x;
  if (i < n4) {
    const float4 v = ((const float4*)in)[i];
    uint2 o;
    o.x = (unsigned)f2bf(v.x) | ((unsigned)f2bf(v.y) << 16);
    o.y = (unsigned)f2bf(v.z) | ((unsigned)f2bf(v.w) << 16);
    ((uint2*)out)[i] = o;
  }
}

// All 4 weight matrices (1024x1024 fp32) -> bf16 transposed, one launch.
__global__ void cvtT_w4(const float* __restrict__ Wq, const float* __restrict__ Wk,
                        const float* __restrict__ Wv, const float* __restrict__ Wo,
                        unsigned short* __restrict__ Wqkvb, unsigned short* __restrict__ Wob) {
  __shared__ unsigned short tile[64][65];
  const int z = blockIdx.z;
  const float* in = (z == 0) ? Wq : (z == 1) ? Wk : (z == 2) ? Wv : Wo;
  unsigned short* out = (z == 3) ? Wob : Wqkvb + (size_t)z * 1024 * 1024;
  const int r0 = blockIdx.y * 64, c0 = blockIdx.x * 64;
  for (int i = threadIdx.y; i < 64; i += 4)
    tile[i][threadIdx.x] = f2bf(in[(size_t)(r0 + i) * 1024 + c0 + threadIdx.x]);
  __syncthreads();
  for (int i = threadIdx.y; i < 64; i += 4)
    out[(size_t)(c0 + i) * 1024 + r0 + threadIdx.x] = tile[threadIdx.x][i];
}

// concat bq|bk|bv into bqkv
__global__ void concat_bias(const float* __restrict__ bq, const float* __restrict__ bk,
                            const float* __restrict__ bv, float* __restrict__ dst) {
  const int z = blockIdx.x;
  const float* src = (z == 0) ? bq : (z == 1) ? bk : bv;
  const int i = threadIdx.x;
  ((float4*)(dst + z * 1024))[i] = ((const float4*)src)[i];
}

// One block per row of 2048 bf16 scores; softmax in fp32, bf16 in place.
__global__ __launch_bounds__(256) void softmax_bf16(unsigned short* __restrict__ scores) {
  unsigned short* p = scores + (size_t)blockIdx.x * 2048;
  const int t = threadIdx.x;
  uint4 raw = ((const uint4*)p)[t];
  float v[8];
  v[0] = __uint_as_float(raw.x << 16); v[1] = __uint_as_float(raw.x & 0xffff0000u);
  v[2] = __uint_as_float(raw.y << 16); v[3] = __uint_as_float(raw.y & 0xffff0000u);
  v[4] = __uint_as_float(raw.z << 16); v[5] = __uint_as_float(raw.z & 0xffff0000u);
  v[6] = __uint_as_float(raw.w << 16); v[7] = __uint_as_float(raw.w & 0xffff0000u);

  float m = v[0];
#pragma unroll
  for (int i = 1; i < 8; ++i) m = fmaxf(m, v[i]);
#pragma unroll
  for (int off = 32; off; off >>= 1) m = fmaxf(m, __shfl_xor(m, off, 64));

  __shared__ float red[4];
  __shared__ float bcast[2];
  const int wave = t >> 6, lane = t & 63;
  if (lane == 0) red[wave] = m;
  __syncthreads();
  if (t == 0) bcast[0] = fmaxf(fmaxf(red[0], red[1]), fmaxf(red[2], red[3]));
  __syncthreads();
  m = bcast[0];

  float s = 0.f;
#pragma unroll
  for (int i = 0; i < 8; ++i) { v[i] = __expf(v[i] - m); s += v[i]; }
#pragma unroll
  for (int off = 32; off; off >>= 1) s += __shfl_xor(s, off, 64);
  if (lane == 0) red[wave] = s;
  __syncthreads();
  if (t == 0) bcast[1] = red[0] + red[1] + red[2] + red[3];
  __syncthreads();
  const float inv = 1.0f / bcast[1];

  uint4 ov;
  ov.x = (unsigned)f2bf(v[0] * inv) | ((unsigned)f2bf(v[1] * inv) << 16);
  ov.y = (unsigned)f2bf(v[2] * inv) | ((unsigned)f2bf(v[3] * inv) << 16);
  ov.z = (unsigned)f2bf(v[4] * inv) | ((unsigned)f2bf(v[5] * inv) << 16);
  ov.w = (unsigned)f2bf(v[6] * inv) | ((unsigned)f2bf(v[7] * inv) << 16);
  ((uint4*)p)[t] = ov;
}

// ---------------------------------------------------------------------------
extern "C" void kernel_launch(void* const* d_in, const int* in_sizes, int n_in,
                              void* d_out, int out_size, void* d_ws, size_t ws_size,
                              hipStream_t stream) {
  const float* x  = (const float*)d_in[0];
  const float* Wq = (const float*)d_in[1];
  const float* bq = (const float*)d_in[2];
  const float* Wk = (const float*)d_in[3];
  const float* bk = (const float*)d_in[4];
  const float* Wv = (const float*)d_in[5];
  const float* bv = (const float*)d_in[6];
  const float* Wo = (const float*)d_in[7];
  const float* bo = (const float*)d_in[8];
  float* out = (float*)d_out;

  char* ws = (char*)d_ws;
  size_t off = 0;
  auto alloc = [&](size_t bytes) { char* p = ws + off; off += (bytes + 255) & ~255UL; return p; };
  unsigned short* xb    = (unsigned short*)alloc(8192UL * 1024 * 2);     // 16 MiB
  unsigned short* Wqkvb = (unsigned short*)alloc(3072UL * 1024 * 2);     // 6 MiB
  unsigned short* Wob   = (unsigned short*)alloc(1024UL * 1024 * 2);     // 2 MiB
  float*          bqkv  = (float*)alloc(3072UL * 4);
  unsigned short* Qb    = (unsigned short*)alloc(8192UL * 1024 * 2);     // 16 MiB (piece 0)
  unsigned short* Kb    = (unsigned short*)alloc(8192UL * 1024 * 2);     // 16 MiB (piece 1, == Qb + sC)
  unsigned short* Vtb   = (unsigned short*)alloc(4UL * 1024 * 2048 * 2); // 16 MiB [b][d][s]
  unsigned short* attn  = (unsigned short*)alloc(8192UL * 2048 * 2);     // 32 MiB bf16 scores
  unsigned short* ctxb  = (unsigned short*)alloc(8192UL * 1024 * 2);     // 16 MiB

  const dim3 blk(512);

  // input convert + all weight transposes + bias concat
  cvt_x<<<2097152 / 256, 256, 0, stream>>>(x, xb, 2097152);
  cvtT_w4<<<dim3(16, 16, 4), dim3(64, 4), 0, stream>>>(Wq, Wk, Wv, Wo, Wqkvb, Wob);
  concat_bias<<<3, 256, 0, stream>>>(bq, bk, bv, bqkv);

  // fused QKV projection: Q,K compact + V transposed to Vtb. 768 blocks.
  gemmk<unsigned short, true, 1><<<dim3(32, 24, 1), blk, 0, stream>>>(
      xb, Wqkvb, Qb, Vtb, bqkv, 1024, 1024, 1024, 1024, 0, 0, 8192L * 1024, 1.0f);

  // scores = (Q @ K^T) / 32 -> bf16, per batch. 512 blocks (1 exact round).
  gemmk<unsigned short, false, 0><<<dim3(8, 16, 4), blk, 0, stream>>>(
      Qb, Kb, attn, nullptr, nullptr, 1024, 1024, 1024, 2048,
      2048L * 1024, 2048L * 1024, 2048L * 2048, 0.03125f);

  // softmax rows in place (bf16, dense ld=2048)
  softmax_bf16<<<8192, 256, 0, stream>>>(attn);

  // ctx = attn @ V  (attn lda=2048, Vt is Bt layout). 256 blocks.
  gemmk<unsigned short, false, 0><<<dim3(8, 8, 4), blk, 0, stream>>>(
      attn, Vtb, ctxb, nullptr, nullptr, 2048, 2048, 2048, 1024,
      2048L * 2048, 1024L * 2048, 2048L * 1024, 1.0f);

  // out = ctx @ Wo + bo (fp32 out). 256 blocks.
  gemmk<float, true, 0><<<dim3(32, 8, 1), blk, 0, stream>>>(
      ctxb, Wob, out, nullptr, bo, 1024, 1024, 1024, 1024, 0, 0, 0, 1.0f);
}

// Round 7
// 283.958 us; speedup vs baseline: 1.1558x; 1.1558x over previous
//
#include <hip/hip_runtime.h>

typedef __attribute__((ext_vector_type(8))) short bf16x8;
typedef __attribute__((ext_vector_type(4))) float f32x4;
typedef __attribute__((ext_vector_type(4))) unsigned short us4;

#define AS1 __attribute__((address_space(1)))
#define AS3 __attribute__((address_space(3)))

__device__ __forceinline__ unsigned short f2bf(float f) {
  unsigned u = __float_as_uint(f);
  u += 0x7fff + ((u >> 16) & 1);   // RNE
  return (unsigned short)(u >> 16);
}

__device__ __forceinline__ void gload_lds16(const void* g, void* l) {
  __builtin_amdgcn_global_load_lds((const AS1 unsigned int*)g,
                                   (AS3 unsigned int*)l, 16, 0, 0);
}

#define MFMA16(a, b, c) __builtin_amdgcn_mfma_f32_16x16x32_bf16(a, b, c, 0, 0, 0)

// ---------------------------------------------------------------------------
// BM=256 x BN=128, BK=32 bf16 GEMM, one window per K-tile, 3-deep LDS ring,
// 72 KB LDS -> 2 blocks/CU.  Round-7 = round-4 EXACTLY + chunk-XOR swizzle
// (Option C): coalesced staging AND conflict-free fragment reads.
// C[M,N] = scale*(A[M,K] @ Bt[N,K]^T) + bias.
// 512 thr = 8 waves (4M x 2N): wm = wave>>1, wn = wave&1; per-wave 64x64 =
// acc[4][4] of 16x16x32 MFMA.
//
// LDS layout: row-major 16-row x 32-col fragment blocks (1 KB), but the
// 16B chunk index is XORed with g(row) = (row>>1)&3:
//   LDS slot (r16, s) of a block holds global chunk (s ^ g(r16)) of row r16.
// Stage (one gload/thread per 128-row call): lane tid fetches global
//   row = tid>>2, chunk = (tid&3) ^ ((tid>>3)&3)   [(tid>>3)&3 == g(row)]
//   -> each 4-lane quad covers one full 64B line (permuted) => coalescing
//   identical to round 4; LDS dest = base + tid*16B (linear, rule 21).
// Read: lane (l15, hi) reads block offset l15*64B + (hi ^ g(l15))*16B.
//   Bank-group = 4*(l15&1) + (hi ^ ((l15>>1)&3)): each of 8 groups hit
//   exactly 2x per 16-lane group == the proven conflict-free distribution.
//
// Window t: stage(t+2) [3 gloads] ; ds_read af[4], bf[4] of tile t ;
// 16 MFMA ; vmcnt(3) ; s_barrier.
//   Steady state at wait: outstanding = 6 -> vmcnt(3) drains exactly
//   stage(t+1), one full window ahead of its reads.  Per-wave vmcnt +
//   barrier => tile complete CU-wide.  Tail: t+2==NT -> vmcnt(0);
//   last window -> no wait.
// WAR: stage(t+2) overwrites buf[(t-1)%3]; its ds_reads were lgkm-drained
// before window t-1's MFMAs, then the end-of-(t-1) barrier was crossed.
//
// MODE 0: C[bz*sC + row*ldc + col].  MODE 1 (fused QKV): piece = col0>>10
// (wave-uniform); pieces 0,1 -> compact [8192][1024] at C + piece*sC;
// piece 2 -> V transposed to Vt[b][d][2048], b = blockIdx.x>>3.
// ---------------------------------------------------------------------------
template <typename OutT, bool BIAS, int MODE>
__global__ __launch_bounds__(512, 2) void gemmk(
    const unsigned short* __restrict__ A,
    const unsigned short* __restrict__ Bt,
    OutT* __restrict__ C,
    unsigned short* __restrict__ Vt,
    const float* __restrict__ bias,
    int Kd, int lda, int ldb, int ldc,
    long sA, long sB, long sC,
    float scale) {
  constexpr int ABUF  = 256 * 32;            // 8192 ushorts (16 KB)
  constexpr int BUFSZ = ABUF + 128 * 32;     // 12288 ushorts = 24 KB
  __shared__ unsigned short lds[3 * BUFSZ];  // 72 KB -> 2 blocks/CU

  const int bz = blockIdx.z;
  A  += (size_t)bz * sA + (size_t)blockIdx.x * 256 * lda;
  Bt += (size_t)bz * sB + (size_t)blockIdx.y * 128 * ldb;

  const int tid  = threadIdx.x;
  const int wave = tid >> 6;
  const int lane = tid & 63;
  const int wm   = wave >> 1;              // 0..3
  const int wn   = wave & 1;               // 0..1
  const int l15  = lane & 15;
  const int hi   = lane >> 4;              // 0..3
  // stage-side: lane covers global (row = tid>>2, chunk = (tid&3)^g(row)),
  // g(row) = (row>>1)&3 = (tid>>3)&3.  Quad = full 64B line, permuted.
  const int srow = tid >> 2;               // 0..127 within a call
  const int schk = ((tid & 3) ^ ((tid >> 3) & 3)) * 8;  // ushort offset

  auto stage = [&](int bi, int k0) {
    unsigned short* L = &lds[bi * BUFSZ + wave * 512];       // wave-uniform
    const unsigned short* ga = A + (size_t)srow * lda + (k0 + schk);
    gload_lds16(ga, L);                                      // A rows 0-127
    gload_lds16(ga + (size_t)128 * lda, L + 4096);           // A rows 128-255
    gload_lds16(Bt + (size_t)srow * ldb + (k0 + schk), L + ABUF);  // B 0-127
  };

  f32x4 acc[4][4] = {};

  // prologue: stage tiles 0,1; drain tile 0 (keep tile 1 in flight)
  stage(0, 0);
  stage(1, 32);
  asm volatile("s_waitcnt vmcnt(3)" ::: "memory");
  __builtin_amdgcn_s_barrier();

  const int NT = Kd >> 5;
  int bufi = 0;
  // read-side swizzled chunk offset: (hi ^ g(l15)) * 8 ushorts
  const int xh  = (hi ^ ((l15 >> 1) & 3)) * 8;
  const int rdA = (wm * 64 + l15) * 32 + xh;          // + mt*512
  const int rdB = ABUF + (wn * 64 + l15) * 32 + xh;   // + nt*512
  for (int t = 0; t < NT; ++t) {
    if (t + 2 < NT) {
      int nbi = bufi + 2; if (nbi >= 3) nbi -= 3;
      stage(nbi, (t + 2) << 5);
    }
    const unsigned short* L = &lds[bufi * BUFSZ];
    bf16x8 af[4], bf[4];
#pragma unroll
    for (int mt = 0; mt < 4; ++mt)
      af[mt] = *(const bf16x8*)&L[rdA + mt * 512];
#pragma unroll
    for (int nt = 0; nt < 4; ++nt)
      bf[nt] = *(const bf16x8*)&L[rdB + nt * 512];
    __builtin_amdgcn_s_setprio(1);
#pragma unroll
    for (int mt = 0; mt < 4; ++mt)
#pragma unroll
      for (int nt = 0; nt < 4; ++nt)
        acc[mt][nt] = MFMA16(af[mt], bf[nt], acc[mt][nt]);
    __builtin_amdgcn_s_setprio(0);
    if (t + 2 < NT)      asm volatile("s_waitcnt vmcnt(3)" ::: "memory");
    else if (t + 1 < NT) asm volatile("s_waitcnt vmcnt(0)" ::: "memory");
    __builtin_amdgcn_s_barrier();
    bufi = (bufi + 1 == 3) ? 0 : bufi + 1;
  }

  // ------------------------------- epilogue -------------------------------
  const int hi4  = hi << 2;
  const int row0 = blockIdx.x * 256 + wm * 64;
  const int col0 = blockIdx.y * 128 + wn * 64;

  if constexpr (MODE == 1) {
    const int piece = col0 >> 10;                 // wave-uniform
    float bvv[4];
#pragma unroll
    for (int nt = 0; nt < 4; ++nt)
      bvv[nt] = BIAS ? bias[col0 + nt * 16 + l15] : 0.0f;
    if (piece < 2) {
      OutT* dst = C + (size_t)piece * sC;
      const int cb = (col0 & 1023) + l15;
#pragma unroll
      for (int mt = 0; mt < 4; ++mt)
#pragma unroll
        for (int r = 0; r < 4; ++r) {
          const size_t rowoff = (size_t)(row0 + mt * 16 + hi4 + r) * ldc;
#pragma unroll
          for (int nt = 0; nt < 4; ++nt)
            dst[rowoff + cb + nt * 16] = (OutT)f2bf(acc[mt][nt][r] * scale + bvv[nt]);
        }
    } else {
      // V piece: write transposed Vt[b][d][2048]
      const int b = blockIdx.x >> 3;
      const int sb = (blockIdx.x & 7) * 256 + wm * 64 + hi4;
#pragma unroll
      for (int nt = 0; nt < 4; ++nt) {
        const int d = ((col0 + nt * 16) & 1023) + l15;
#pragma unroll
        for (int mt = 0; mt < 4; ++mt) {
          us4 pk;
          pk.x = f2bf(acc[mt][nt][0] * scale + bvv[nt]);
          pk.y = f2bf(acc[mt][nt][1] * scale + bvv[nt]);
          pk.z = f2bf(acc[mt][nt][2] * scale + bvv[nt]);
          pk.w = f2bf(acc[mt][nt][3] * scale + bvv[nt]);
          *(us4*)&Vt[((size_t)b << 21) + (size_t)d * 2048 + sb + mt * 16] = pk;
        }
      }
    }
  } else {
    C += (size_t)bz * sC;
    float bvv[4];
#pragma unroll
    for (int nt = 0; nt < 4; ++nt)
      bvv[nt] = BIAS ? bias[col0 + nt * 16 + l15] : 0.0f;
    const int cb = col0 + l15;
#pragma unroll
    for (int mt = 0; mt < 4; ++mt)
#pragma unroll
      for (int r = 0; r < 4; ++r) {
        const size_t rowoff = (size_t)(row0 + mt * 16 + hi4 + r) * ldc;
#pragma unroll
        for (int nt = 0; nt < 4; ++nt) {
          const float v = acc[mt][nt][r] * scale + bvv[nt];
          if constexpr (sizeof(OutT) == 4)
            C[rowoff + cb + nt * 16] = v;
          else
            C[rowoff + cb + nt * 16] = (OutT)f2bf(v);
        }
      }
  }
}

// fp32 -> bf16 flat convert (4 elems/thread)
__global__ void cvt_x(const float* __restrict__ in, unsigned short* __restrict__ out, int n4) {
  const int i = blockIdx.x * blockDim.x + threadIdx.x;
  if (i < n4) {
    const float4 v = ((const float4*)in)[i];
    uint2 o;
    o.x = (unsigned)f2bf(v.x) | ((unsigned)f2bf(v.y) << 16);
    o.y = (unsigned)f2bf(v.z) | ((unsigned)f2bf(v.w) << 16);
    ((uint2*)out)[i] = o;
  }
}

// All 4 weight matrices (1024x1024 fp32) -> bf16 transposed, one launch.
__global__ void cvtT_w4(const float* __restrict__ Wq, const float* __restrict__ Wk,
                        const float* __restrict__ Wv, const float* __restrict__ Wo,
                        unsigned short* __restrict__ Wqkvb, unsigned short* __restrict__ Wob) {
  __shared__ unsigned short tile[64][65];
  const int z = blockIdx.z;
  const float* in = (z == 0) ? Wq : (z == 1) ? Wk : (z == 2) ? Wv : Wo;
  unsigned short* out = (z == 3) ? Wob : Wqkvb + (size_t)z * 1024 * 1024;
  const int r0 = blockIdx.y * 64, c0 = blockIdx.x * 64;
  for (int i = threadIdx.y; i < 64; i += 4)
    tile[i][threadIdx.x] = f2bf(in[(size_t)(r0 + i) * 1024 + c0 + threadIdx.x]);
  __syncthreads();
  for (int i = threadIdx.y; i < 64; i += 4)
    out[(size_t)(c0 + i) * 1024 + r0 + threadIdx.x] = tile[threadIdx.x][i];
}

// concat bq|bk|bv into bqkv
__global__ void concat_bias(const float* __restrict__ bq, const float* __restrict__ bk,
                            const float* __restrict__ bv, float* __restrict__ dst) {
  const int z = blockIdx.x;
  const float* src = (z == 0) ? bq : (z == 1) ? bk : bv;
  const int i = threadIdx.x;
  ((float4*)(dst + z * 1024))[i] = ((const float4*)src)[i];
}

// One block per row of 2048 bf16 scores; softmax in fp32, bf16 in place.
__global__ __launch_bounds__(256) void softmax_bf16(unsigned short* __restrict__ scores) {
  unsigned short* p = scores + (size_t)blockIdx.x * 2048;
  const int t = threadIdx.x;
  uint4 raw = ((const uint4*)p)[t];
  float v[8];
  v[0] = __uint_as_float(raw.x << 16); v[1] = __uint_as_float(raw.x & 0xffff0000u);
  v[2] = __uint_as_float(raw.y << 16); v[3] = __uint_as_float(raw.y & 0xffff0000u);
  v[4] = __uint_as_float(raw.z << 16); v[5] = __uint_as_float(raw.z & 0xffff0000u);
  v[6] = __uint_as_float(raw.w << 16); v[7] = __uint_as_float(raw.w & 0xffff0000u);

  float m = v[0];
#pragma unroll
  for (int i = 1; i < 8; ++i) m = fmaxf(m, v[i]);
#pragma unroll
  for (int off = 32; off; off >>= 1) m = fmaxf(m, __shfl_xor(m, off, 64));

  __shared__ float red[4];
  __shared__ float bcast[2];
  const int wave = t >> 6, lane = t & 63;
  if (lane == 0) red[wave] = m;
  __syncthreads();
  if (t == 0) bcast[0] = fmaxf(fmaxf(red[0], red[1]), fmaxf(red[2], red[3]));
  __syncthreads();
  m = bcast[0];

  float s = 0.f;
#pragma unroll
  for (int i = 0; i < 8; ++i) { v[i] = __expf(v[i] - m); s += v[i]; }
#pragma unroll
  for (int off = 32; off; off >>= 1) s += __shfl_xor(s, off, 64);
  if (lane == 0) red[wave] = s;
  __syncthreads();
  if (t == 0) bcast[1] = red[0] + red[1] + red[2] + red[3];
  __syncthreads();
  const float inv = 1.0f / bcast[1];

  uint4 ov;
  ov.x = (unsigned)f2bf(v[0] * inv) | ((unsigned)f2bf(v[1] * inv) << 16);
  ov.y = (unsigned)f2bf(v[2] * inv) | ((unsigned)f2bf(v[3] * inv) << 16);
  ov.z = (unsigned)f2bf(v[4] * inv) | ((unsigned)f2bf(v[5] * inv) << 16);
  ov.w = (unsigned)f2bf(v[6] * inv) | ((unsigned)f2bf(v[7] * inv) << 16);
  ((uint4*)p)[t] = ov;
}

// ---------------------------------------------------------------------------
extern "C" void kernel_launch(void* const* d_in, const int* in_sizes, int n_in,
                              void* d_out, int out_size, void* d_ws, size_t ws_size,
                              hipStream_t stream) {
  const float* x  = (const float*)d_in[0];
  const float* Wq = (const float*)d_in[1];
  const float* bq = (const float*)d_in[2];
  const float* Wk = (const float*)d_in[3];
  const float* bk = (const float*)d_in[4];
  const float* Wv = (const float*)d_in[5];
  const float* bv = (const float*)d_in[6];
  const float* Wo = (const float*)d_in[7];
  const float* bo = (const float*)d_in[8];
  float* out = (float*)d_out;

  char* ws = (char*)d_ws;
  size_t off = 0;
  auto alloc = [&](size_t bytes) { char* p = ws + off; off += (bytes + 255) & ~255UL; return p; };
  unsigned short* xb    = (unsigned short*)alloc(8192UL * 1024 * 2);     // 16 MiB
  unsigned short* Wqkvb = (unsigned short*)alloc(3072UL * 1024 * 2);     // 6 MiB
  unsigned short* Wob   = (unsigned short*)alloc(1024UL * 1024 * 2);     // 2 MiB
  float*          bqkv  = (float*)alloc(3072UL * 4);
  unsigned short* Qb    = (unsigned short*)alloc(8192UL * 1024 * 2);     // 16 MiB (piece 0)
  unsigned short* Kb    = (unsigned short*)alloc(8192UL * 1024 * 2);     // 16 MiB (piece 1, == Qb + sC)
  unsigned short* Vtb   = (unsigned short*)alloc(4UL * 1024 * 2048 * 2); // 16 MiB [b][d][s]
  unsigned short* attn  = (unsigned short*)alloc(8192UL * 2048 * 2);     // 32 MiB bf16 scores
  unsigned short* ctxb  = (unsigned short*)alloc(8192UL * 1024 * 2);     // 16 MiB

  const dim3 blk(512);

  // input convert + all weight transposes + bias concat
  cvt_x<<<2097152 / 256, 256, 0, stream>>>(x, xb, 2097152);
  cvtT_w4<<<dim3(16, 16, 4), dim3(64, 4), 0, stream>>>(Wq, Wk, Wv, Wo, Wqkvb, Wob);
  concat_bias<<<3, 256, 0, stream>>>(bq, bk, bv, bqkv);

  // fused QKV projection: Q,K compact + V transposed to Vtb. 768 blocks.
  gemmk<unsigned short, true, 1><<<dim3(32, 24, 1), blk, 0, stream>>>(
      xb, Wqkvb, Qb, Vtb, bqkv, 1024, 1024, 1024, 1024, 0, 0, 8192L * 1024, 1.0f);

  // scores = (Q @ K^T) / 32 -> bf16, per batch. 512 blocks.
  gemmk<unsigned short, false, 0><<<dim3(8, 16, 4), blk, 0, stream>>>(
      Qb, Kb, attn, nullptr, nullptr, 1024, 1024, 1024, 2048,
      2048L * 1024, 2048L * 1024, 2048L * 2048, 0.03125f);

  // softmax rows in place (bf16, dense ld=2048)
  softmax_bf16<<<8192, 256, 0, stream>>>(attn);

  // ctx = attn @ V  (attn lda=2048, Vt is Bt layout). 256 blocks.
  gemmk<unsigned short, false, 0><<<dim3(8, 8, 4), blk, 0, stream>>>(
      attn, Vtb, ctxb, nullptr, nullptr, 2048, 2048, 2048, 1024,
      2048L * 2048, 1024L * 2048, 2048L * 1024, 1.0f);

  // out = ctx @ Wo + bo (fp32 out). 256 blocks.
  gemmk<float, true, 0><<<dim3(32, 8, 1), blk, 0, stream>>>(
      ctxb, Wob, out, nullptr, bo, 1024, 1024, 1024, 1024, 0, 0, 0, 1.0f);
}

// Round 8
// 280.879 us; speedup vs baseline: 1.1684x; 1.0110x over previous
//
#include <hip/hip_runtime.h>

typedef __attribute__((ext_vector_type(8))) short bf16x8;
typedef __attribute__((ext_vector_type(4))) float f32x4;
typedef __attribute__((ext_vector_type(4))) unsigned short us4;

#define AS1 __attribute__((address_space(1)))
#define AS3 __attribute__((address_space(3)))

__device__ __forceinline__ unsigned short f2bf(float f) {
  unsigned u = __float_as_uint(f);
  u += 0x7fff + ((u >> 16) & 1);   // RNE
  return (unsigned short)(u >> 16);
}

__device__ __forceinline__ void gload_lds16(const void* g, void* l) {
  __builtin_amdgcn_global_load_lds((const AS1 unsigned int*)g,
                                   (AS3 unsigned int*)l, 16, 0, 0);
}

#define MFMA16(a, b, c) __builtin_amdgcn_mfma_f32_16x16x32_bf16(a, b, c, 0, 0, 0)

// ---------------------------------------------------------------------------
// BM (template: 256 or 128) x BN=128, BK=32 bf16 GEMM, one window per K-tile,
// 3-deep LDS ring.  C[M,N] = scale*(A[M,K] @ Bt[N,K]^T) + bias.
// THREADS = 2*BM (512 or 256) = 8 or 4 waves (wm=wave>>1, wn=wave&1);
// per-wave 64x64 = acc[4][4] of 16x16x32 MFMA.
//   BM=256: LDS 72 KB -> 2 blocks/CU.   BM=128: LDS 48 KB -> 3 blocks/CU
//   (full machine for N=1024 outputs: grid 512 blocks).
//
// LDS layout (round-7, verified 0 conflicts + coalesced staging): row-major
// 16-row x 32-col fragment blocks (1 KB); 16B chunk index XORed with
// g(row) = (row>>1)&3.
// Stage (one gload/thread per call of THREADS/4 rows): lane tid fetches
//   global row = tid>>2, chunk = (tid&3) ^ ((tid>>3)&3)  [== g(row)]
//   -> each 4-lane quad covers one full (permuted) 64B line => coalesced;
//   LDS dest = base + tid*16B (linear, rule 21).
// Read: lane (l15, hi) reads block offset l15*64B + (hi ^ g(l15))*16B
//   -> same bank distribution as linear (verified SQ_LDS_BANK_CONFLICT=0).
// Calls/tile: A: BM/(THREADS/4) = 2, B: 128/(THREADS/4) = 1 or 2
//   -> LOADS = 3 (BM=256) or 4 (BM=128).
//
// Window t: stage(t+2) [LOADS gloads] ; ds_read af[4], bf[4] of tile t ;
// 16 MFMA ; vmcnt(LOADS) ; s_barrier.
//   Steady state at wait: outstanding = 2*LOADS -> vmcnt(LOADS) drains
//   exactly stage(t+1), one full window ahead of its reads.  Per-wave vmcnt
//   + barrier => tile complete CU-wide.  Tail: t+2==NT -> vmcnt(0); last
//   window -> no wait.
// WAR: stage(t+2) overwrites buf[(t-1)%3]; its ds_reads were lgkm-drained
// before window t-1's MFMAs, then the end-of-(t-1) barrier was crossed.
//
// MODE 0: C[bz*sC + row*ldc + col].  MODE 1 (fused QKV, BM=256 only):
// piece = col0>>10 (wave-uniform); pieces 0,1 -> compact [8192][1024] at
// C + piece*sC; piece 2 -> V transposed to Vt[b][d][2048], b = blockIdx.x>>3.
// ---------------------------------------------------------------------------
template <typename OutT, bool BIAS, int MODE, int BM>
__global__ __launch_bounds__(2 * BM, (BM == 256) ? 2 : 3) void gemmk(
    const unsigned short* __restrict__ A,
    const unsigned short* __restrict__ Bt,
    OutT* __restrict__ C,
    unsigned short* __restrict__ Vt,
    const float* __restrict__ bias,
    int Kd, int lda, int ldb, int ldc,
    long sA, long sB, long sC,
    float scale) {
  constexpr int THREADS = 2 * BM;
  constexpr int ABUF  = BM * 32;             // ushorts
  constexpr int BUFSZ = ABUF + 128 * 32;     // ushorts
  __shared__ unsigned short lds[3 * BUFSZ];  // 72 KB / 48 KB

  const int bz = blockIdx.z;
  A  += (size_t)bz * sA + (size_t)blockIdx.x * BM * lda;
  Bt += (size_t)bz * sB + (size_t)blockIdx.y * 128 * ldb;

  const int tid  = threadIdx.x;
  const int wave = tid >> 6;
  const int lane = tid & 63;
  const int wm   = wave >> 1;              // 0..3 / 0..1
  const int wn   = wave & 1;               // 0..1
  const int l15  = lane & 15;
  const int hi   = lane >> 4;              // 0..3
  // stage-side: lane covers global (row = tid>>2, chunk = (tid&3)^g(row))
  const int srow = tid >> 2;               // 0..THREADS/4-1 within a call
  const int schk = ((tid & 3) ^ ((tid >> 3) & 3)) * 8;  // ushort offset

  auto stage = [&](int bi, int k0) {
    unsigned short* L = &lds[bi * BUFSZ + wave * 512];       // wave-uniform
    const unsigned short* ga = A + (size_t)srow * lda + (k0 + schk);
    const unsigned short* gb = Bt + (size_t)srow * ldb + (k0 + schk);
    if constexpr (BM == 256) {
      gload_lds16(ga, L);                                    // A rows 0-127
      gload_lds16(ga + (size_t)128 * lda, L + 4096);         // A rows 128-255
      gload_lds16(gb, L + ABUF);                             // B rows 0-127
    } else {
      gload_lds16(ga, L);                                    // A rows 0-63
      gload_lds16(ga + (size_t)64 * lda, L + 2048);          // A rows 64-127
      gload_lds16(gb, L + ABUF);                             // B rows 0-63
      gload_lds16(gb + (size_t)64 * ldb, L + ABUF + 2048);   // B rows 64-127
    }
  };

  f32x4 acc[4][4] = {};

  // prologue: stage tiles 0,1; drain tile 0 (keep tile 1 in flight)
  stage(0, 0);
  stage(1, 32);
  if constexpr (BM == 256) asm volatile("s_waitcnt vmcnt(3)" ::: "memory");
  else                     asm volatile("s_waitcnt vmcnt(4)" ::: "memory");
  __builtin_amdgcn_s_barrier();

  const int NT = Kd >> 5;
  int bufi = 0;
  // read-side swizzled chunk offset: (hi ^ g(l15)) * 8 ushorts
  const int xh  = (hi ^ ((l15 >> 1) & 3)) * 8;
  const int rdA = (wm * 64 + l15) * 32 + xh;          // + mt*512
  const int rdB = ABUF + (wn * 64 + l15) * 32 + xh;   // + nt*512
  for (int t = 0; t < NT; ++t) {
    if (t + 2 < NT) {
      int nbi = bufi + 2; if (nbi >= 3) nbi -= 3;
      stage(nbi, (t + 2) << 5);
    }
    const unsigned short* L = &lds[bufi * BUFSZ];
    bf16x8 af[4], bf[4];
#pragma unroll
    for (int mt = 0; mt < 4; ++mt)
      af[mt] = *(const bf16x8*)&L[rdA + mt * 512];
#pragma unroll
    for (int nt = 0; nt < 4; ++nt)
      bf[nt] = *(const bf16x8*)&L[rdB + nt * 512];
    __builtin_amdgcn_s_setprio(1);
#pragma unroll
    for (int mt = 0; mt < 4; ++mt)
#pragma unroll
      for (int nt = 0; nt < 4; ++nt)
        acc[mt][nt] = MFMA16(af[mt], bf[nt], acc[mt][nt]);
    __builtin_amdgcn_s_setprio(0);
    if (t + 2 < NT) {
      if constexpr (BM == 256) asm volatile("s_waitcnt vmcnt(3)" ::: "memory");
      else                     asm volatile("s_waitcnt vmcnt(4)" ::: "memory");
    } else if (t + 1 < NT) {
      asm volatile("s_waitcnt vmcnt(0)" ::: "memory");
    }
    __builtin_amdgcn_s_barrier();
    bufi = (bufi + 1 == 3) ? 0 : bufi + 1;
  }

  // ------------------------------- epilogue -------------------------------
  const int hi4  = hi << 2;
  const int row0 = blockIdx.x * BM + wm * 64;
  const int col0 = blockIdx.y * 128 + wn * 64;

  if constexpr (MODE == 1) {
    const int piece = col0 >> 10;                 // wave-uniform
    float bvv[4];
#pragma unroll
    for (int nt = 0; nt < 4; ++nt)
      bvv[nt] = BIAS ? bias[col0 + nt * 16 + l15] : 0.0f;
    if (piece < 2) {
      OutT* dst = C + (size_t)piece * sC;
      const int cb = (col0 & 1023) + l15;
#pragma unroll
      for (int mt = 0; mt < 4; ++mt)
#pragma unroll
        for (int r = 0; r < 4; ++r) {
          const size_t rowoff = (size_t)(row0 + mt * 16 + hi4 + r) * ldc;
#pragma unroll
          for (int nt = 0; nt < 4; ++nt)
            dst[rowoff + cb + nt * 16] = (OutT)f2bf(acc[mt][nt][r] * scale + bvv[nt]);
        }
    } else {
      // V piece: write transposed Vt[b][d][2048]
      const int b = blockIdx.x >> 3;
      const int sb = (blockIdx.x & 7) * 256 + wm * 64 + hi4;
#pragma unroll
      for (int nt = 0; nt < 4; ++nt) {
        const int d = ((col0 + nt * 16) & 1023) + l15;
#pragma unroll
        for (int mt = 0; mt < 4; ++mt) {
          us4 pk;
          pk.x = f2bf(acc[mt][nt][0] * scale + bvv[nt]);
          pk.y = f2bf(acc[mt][nt][1] * scale + bvv[nt]);
          pk.z = f2bf(acc[mt][nt][2] * scale + bvv[nt]);
          pk.w = f2bf(acc[mt][nt][3] * scale + bvv[nt]);
          *(us4*)&Vt[((size_t)b << 21) + (size_t)d * 2048 + sb + mt * 16] = pk;
        }
      }
    }
  } else {
    C += (size_t)bz * sC;
    float bvv[4];
#pragma unroll
    for (int nt = 0; nt < 4; ++nt)
      bvv[nt] = BIAS ? bias[col0 + nt * 16 + l15] : 0.0f;
    const int cb = col0 + l15;
#pragma unroll
    for (int mt = 0; mt < 4; ++mt)
#pragma unroll
      for (int r = 0; r < 4; ++r) {
        const size_t rowoff = (size_t)(row0 + mt * 16 + hi4 + r) * ldc;
#pragma unroll
        for (int nt = 0; nt < 4; ++nt) {
          const float v = acc[mt][nt][r] * scale + bvv[nt];
          if constexpr (sizeof(OutT) == 4)
            C[rowoff + cb + nt * 16] = v;
          else
            C[rowoff + cb + nt * 16] = (OutT)f2bf(v);
        }
      }
  }
}

// fp32 -> bf16 flat convert (4 elems/thread)
__global__ void cvt_x(const float* __restrict__ in, unsigned short* __restrict__ out, int n4) {
  const int i = blockIdx.x * blockDim.x + threadIdx.x;
  if (i < n4) {
    const float4 v = ((const float4*)in)[i];
    uint2 o;
    o.x = (unsigned)f2bf(v.x) | ((unsigned)f2bf(v.y) << 16);
    o.y = (unsigned)f2bf(v.z) | ((unsigned)f2bf(v.w) << 16);
    ((uint2*)out)[i] = o;
  }
}

// All 4 weight matrices (1024x1024 fp32) -> bf16 transposed, one launch.
__global__ void cvtT_w4(const float* __restrict__ Wq, const float* __restrict__ Wk,
                        const float* __restrict__ Wv, const float* __restrict__ Wo,
                        unsigned short* __restrict__ Wqkvb, unsigned short* __restrict__ Wob) {
  __shared__ unsigned short tile[64][65];
  const int z = blockIdx.z;
  const float* in = (z == 0) ? Wq : (z == 1) ? Wk : (z == 2) ? Wv : Wo;
  unsigned short* out = (z == 3) ? Wob : Wqkvb + (size_t)z * 1024 * 1024;
  const int r0 = blockIdx.y * 64, c0 = blockIdx.x * 64;
  for (int i = threadIdx.y; i < 64; i += 4)
    tile[i][threadIdx.x] = f2bf(in[(size_t)(r0 + i) * 1024 + c0 + threadIdx.x]);
  __syncthreads();
  for (int i = threadIdx.y; i < 64; i += 4)
    out[(size_t)(c0 + i) * 1024 + r0 + threadIdx.x] = tile[threadIdx.x][i];
}

// concat bq|bk|bv into bqkv
__global__ void concat_bias(const float* __restrict__ bq, const float* __restrict__ bk,
                            const float* __restrict__ bv, float* __restrict__ dst) {
  const int z = blockIdx.x;
  const float* src = (z == 0) ? bq : (z == 1) ? bk : bv;
  const int i = threadIdx.x;
  ((float4*)(dst + z * 1024))[i] = ((const float4*)src)[i];
}

// Softmax, one WAVE per 2048-elem bf16 row (lane holds 32 elems), pure
// shfl reductions: no LDS, no barriers. 8 rows per 512-thr block.
__global__ __launch_bounds__(512) void softmax_w(unsigned short* __restrict__ scores) {
  const int lane = threadIdx.x & 63;
  unsigned short* p =
      scores + ((size_t)blockIdx.x * 8 + (threadIdx.x >> 6)) * 2048;
  uint4 raw[4];
  float v[32];
#pragma unroll
  for (int g = 0; g < 4; ++g) raw[g] = ((const uint4*)p)[lane + g * 64];
#pragma unroll
  for (int g = 0; g < 4; ++g) {
    v[g * 8 + 0] = __uint_as_float(raw[g].x << 16);
    v[g * 8 + 1] = __uint_as_float(raw[g].x & 0xffff0000u);
    v[g * 8 + 2] = __uint_as_float(raw[g].y << 16);
    v[g * 8 + 3] = __uint_as_float(raw[g].y & 0xffff0000u);
    v[g * 8 + 4] = __uint_as_float(raw[g].z << 16);
    v[g * 8 + 5] = __uint_as_float(raw[g].z & 0xffff0000u);
    v[g * 8 + 6] = __uint_as_float(raw[g].w << 16);
    v[g * 8 + 7] = __uint_as_float(raw[g].w & 0xffff0000u);
  }
  float m = v[0];
#pragma unroll
  for (int i = 1; i < 32; ++i) m = fmaxf(m, v[i]);
#pragma unroll
  for (int off = 32; off; off >>= 1) m = fmaxf(m, __shfl_xor(m, off, 64));
  float s = 0.f;
#pragma unroll
  for (int i = 0; i < 32; ++i) { v[i] = __expf(v[i] - m); s += v[i]; }
#pragma unroll
  for (int off = 32; off; off >>= 1) s += __shfl_xor(s, off, 64);
  const float inv = 1.0f / s;
#pragma unroll
  for (int g = 0; g < 4; ++g) {
    uint4 ov;
    ov.x = (unsigned)f2bf(v[g * 8 + 0] * inv) | ((unsigned)f2bf(v[g * 8 + 1] * inv) << 16);
    ov.y = (unsigned)f2bf(v[g * 8 + 2] * inv) | ((unsigned)f2bf(v[g * 8 + 3] * inv) << 16);
    ov.z = (unsigned)f2bf(v[g * 8 + 4] * inv) | ((unsigned)f2bf(v[g * 8 + 5] * inv) << 16);
    ov.w = (unsigned)f2bf(v[g * 8 + 6] * inv) | ((unsigned)f2bf(v[g * 8 + 7] * inv) << 16);
    ((uint4*)p)[lane + g * 64] = ov;
  }
}

// ---------------------------------------------------------------------------
extern "C" void kernel_launch(void* const* d_in, const int* in_sizes, int n_in,
                              void* d_out, int out_size, void* d_ws, size_t ws_size,
                              hipStream_t stream) {
  const float* x  = (const float*)d_in[0];
  const float* Wq = (const float*)d_in[1];
  const float* bq = (const float*)d_in[2];
  const float* Wk = (const float*)d_in[3];
  const float* bk = (const float*)d_in[4];
  const float* Wv = (const float*)d_in[5];
  const float* bv = (const float*)d_in[6];
  const float* Wo = (const float*)d_in[7];
  const float* bo = (const float*)d_in[8];
  float* out = (float*)d_out;

  char* ws = (char*)d_ws;
  size_t off = 0;
  auto alloc = [&](size_t bytes) { char* p = ws + off; off += (bytes + 255) & ~255UL; return p; };
  unsigned short* xb    = (unsigned short*)alloc(8192UL * 1024 * 2);     // 16 MiB
  unsigned short* Wqkvb = (unsigned short*)alloc(3072UL * 1024 * 2);     // 6 MiB
  unsigned short* Wob   = (unsigned short*)alloc(1024UL * 1024 * 2);     // 2 MiB
  float*          bqkv  = (float*)alloc(3072UL * 4);
  unsigned short* Qb    = (unsigned short*)alloc(8192UL * 1024 * 2);     // 16 MiB (piece 0)
  unsigned short* Kb    = (unsigned short*)alloc(8192UL * 1024 * 2);     // 16 MiB (piece 1, == Qb + sC)
  unsigned short* Vtb   = (unsigned short*)alloc(4UL * 1024 * 2048 * 2); // 16 MiB [b][d][s]
  unsigned short* attn  = (unsigned short*)alloc(8192UL * 2048 * 2);     // 32 MiB bf16 scores
  unsigned short* ctxb  = (unsigned short*)alloc(8192UL * 1024 * 2);     // 16 MiB

  // input convert + all weight transposes + bias concat
  cvt_x<<<2097152 / 256, 256, 0, stream>>>(x, xb, 2097152);
  cvtT_w4<<<dim3(16, 16, 4), dim3(64, 4), 0, stream>>>(Wq, Wk, Wv, Wo, Wqkvb, Wob);
  concat_bias<<<3, 256, 0, stream>>>(bq, bk, bv, bqkv);

  // fused QKV projection: Q,K compact + V transposed to Vtb. 768 blocks.
  gemmk<unsigned short, true, 1, 256><<<dim3(32, 24, 1), 512, 0, stream>>>(
      xb, Wqkvb, Qb, Vtb, bqkv, 1024, 1024, 1024, 1024, 0, 0, 8192L * 1024, 1.0f);

  // scores = (Q @ K^T) / 32 -> bf16, per batch. 512 blocks.
  gemmk<unsigned short, false, 0, 256><<<dim3(8, 16, 4), 512, 0, stream>>>(
      Qb, Kb, attn, nullptr, nullptr, 1024, 1024, 1024, 2048,
      2048L * 1024, 2048L * 1024, 2048L * 2048, 0.03125f);

  // softmax: one wave per row, 8 rows/block, no barriers. 1024 blocks.
  softmax_w<<<1024, 512, 0, stream>>>(attn);

  // ctx = attn @ V (attn lda=2048, Vt is Bt layout). BM=128: 512 blocks.
  gemmk<unsigned short, false, 0, 128><<<dim3(16, 8, 4), 256, 0, stream>>>(
      attn, Vtb, ctxb, nullptr, nullptr, 2048, 2048, 2048, 1024,
      2048L * 2048, 1024L * 2048, 2048L * 1024, 1.0f);

  // out = ctx @ Wo + bo (fp32 out). BM=128: 512 blocks.
  gemmk<float, true, 0, 128><<<dim3(64, 8, 1), 256, 0, stream>>>(
      ctxb, Wob, out, nullptr, bo, 1024, 1024, 1024, 1024, 0, 0, 0, 1.0f);
}